// Round 12
// baseline (1259.856 us; speedup 1.0000x reference)
//
#include <hip/hip_runtime.h>
#include <hip/hip_bf16.h>

#define D_MODEL 2048
#define NUM_HEADS 16
#define D_FF 8192
#define BATCH 4
#define SEQ 2048
#define DK 128
#define MTOT (BATCH * SEQ)  // 8192

typedef __attribute__((ext_vector_type(8))) short short8;
typedef __attribute__((ext_vector_type(4))) short short4v;
typedef __attribute__((ext_vector_type(4))) float f32x4;

#define MFMA16(a, b, c) __builtin_amdgcn_mfma_f32_16x16x32_bf16(a, b, c, 0, 0, 0)

#define GLOAD16(gp, lp)                                                        \
  __builtin_amdgcn_global_load_lds(                                            \
      (const __attribute__((address_space(1))) void*)(gp),                     \
      (__attribute__((address_space(3))) void*)(lp), 16, 0, 0)

static __device__ __forceinline__ unsigned short f2bf(float f) {
  return __builtin_bit_cast(unsigned short, __float2bfloat16(f));
}

// ---------------------------------------------------------------------------
// Weight convert + transpose: in f32 [K][N] -> out bf16 [N][K]
// ---------------------------------------------------------------------------
__global__ __launch_bounds__(256) void transpose_cvt_kernel(
    const float* __restrict__ in, __hip_bfloat16* __restrict__ out, int K, int N) {
  __shared__ float tile[32][33];
  const int n0 = blockIdx.x * 32, k0 = blockIdx.y * 32;
  const int tx = threadIdx.x & 31, ty = threadIdx.x >> 5;  // 32 x 8
#pragma unroll
  for (int i = 0; i < 4; ++i)
    tile[ty + i * 8][tx] = in[(size_t)(k0 + ty + i * 8) * N + n0 + tx];
  __syncthreads();
#pragma unroll
  for (int i = 0; i < 4; ++i)
    out[(size_t)(n0 + ty + i * 8) * K + k0 + tx] = __float2bfloat16(tile[tx][ty + i * 8]);
}

// ---------------------------------------------------------------------------
// LayerNorm: f32 [M][D_MODEL] -> bf16 [M][D_MODEL]
// ---------------------------------------------------------------------------
__global__ __launch_bounds__(256) void layernorm_kernel(
    const float* __restrict__ x, const float* __restrict__ g,
    const float* __restrict__ bta, __hip_bfloat16* __restrict__ out) {
  const int row = blockIdx.x;
  const int tid = threadIdx.x;
  const float* xr = x + (size_t)row * D_MODEL;
  float4 v0 = *(const float4*)(xr + tid * 8);
  float4 v1 = *(const float4*)(xr + tid * 8 + 4);
  float s = v0.x + v0.y + v0.z + v0.w + v1.x + v1.y + v1.z + v1.w;
  float q = v0.x * v0.x + v0.y * v0.y + v0.z * v0.z + v0.w * v0.w +
            v1.x * v1.x + v1.y * v1.y + v1.z * v1.z + v1.w * v1.w;
#pragma unroll
  for (int off = 1; off < 64; off <<= 1) {
    s += __shfl_xor(s, off);
    q += __shfl_xor(q, off);
  }
  __shared__ float rs[4], rq[4];
  if ((tid & 63) == 0) {
    rs[tid >> 6] = s;
    rq[tid >> 6] = q;
  }
  __syncthreads();
  s = rs[0] + rs[1] + rs[2] + rs[3];
  q = rq[0] + rq[1] + rq[2] + rq[3];
  const float mu = s * (1.0f / D_MODEL);
  const float var = q * (1.0f / D_MODEL) - mu * mu;
  const float rstd = rsqrtf(var + 1e-5f);
  float4 g0 = *(const float4*)(g + tid * 8);
  float4 g1 = *(const float4*)(g + tid * 8 + 4);
  float4 b0 = *(const float4*)(bta + tid * 8);
  float4 b1 = *(const float4*)(bta + tid * 8 + 4);
  short8 o;
  o[0] = (short)f2bf((v0.x - mu) * rstd * g0.x + b0.x);
  o[1] = (short)f2bf((v0.y - mu) * rstd * g0.y + b0.y);
  o[2] = (short)f2bf((v0.z - mu) * rstd * g0.z + b0.z);
  o[3] = (short)f2bf((v0.w - mu) * rstd * g0.w + b0.w);
  o[4] = (short)f2bf((v1.x - mu) * rstd * g1.x + b1.x);
  o[5] = (short)f2bf((v1.y - mu) * rstd * g1.y + b1.y);
  o[6] = (short)f2bf((v1.z - mu) * rstd * g1.z + b1.z);
  o[7] = (short)f2bf((v1.w - mu) * rstd * g1.w + b1.w);
  *(short8*)(out + (size_t)row * D_MODEL + tid * 8) = o;
}

// ---------------------------------------------------------------------------
// GEMM v6: 256x256 tile, BK=64, 8 waves (2Mx4N), double-buffered LDS (128K).
// Software-pipelined 4-phase schedule: each phase's af ds_reads are issued
// ONE PHASE EARLY (ping-pong afA/afB), so they drain during the previous
// phase's MFMA block instead of serially before it (m196's fine-interleave
// lever). vmcnt(6) moved to P2-end so P3 can preread tile t+1's A-q0.
// Race audit (all hold):
//  - region A-qX(t) preread completes by phase X's lgkmcnt(0), one barrier
//    before stage(t+2, A-qX) is issued (P1:q0, P2:q1, P3:q2, nextP0:q3).
//  - B(t) read wholly at P0, complete by P0 lgkmcnt(0); staged P1/P2.
//  - vmcnt(6)@P2 (outstanding = stage(t+2)'s 6) retires all stage(t+1) ->
//    P3's preread of buf[(t+1)&1] and t+1.P0's bf reads are safe after the
//    P2-end barrier. Tail: vmcnt(0) when no t+2 stages.
// XCD decode (4r x 8c concurrent window per XCD) as round 10.
// ---------------------------------------------------------------------------
enum { EPI_BF16 = 0, EPI_VT = 1, EPI_RESID = 2, EPI_GELU = 3 };

#define READ_AF(dst, dbp, FI0)                                                 \
  {                                                                            \
    const int raA = wm + (FI0) * 16 + l15;                                     \
    const int raB = wm + ((FI0) + 1) * 16 + l15;                               \
    dst[0] = *(const short8*)((dbp) + raA * 128 + ((lg ^ (raA & 7)) << 4));    \
    dst[1] = *(const short8*)((dbp) + raB * 128 + ((lg ^ (raB & 7)) << 4));    \
    dst[2] =                                                                   \
        *(const short8*)((dbp) + raA * 128 + (((4 + lg) ^ (raA & 7)) << 4));   \
    dst[3] =                                                                   \
        *(const short8*)((dbp) + raB * 128 + (((4 + lg) ^ (raB & 7)) << 4));   \
  }

#define MFMA_BLOCK(src, FI0)                                                   \
  {                                                                            \
    __builtin_amdgcn_s_setprio(1);                                             \
    _Pragma("unroll") for (int fj = 0; fj < 4; ++fj)                           \
        acc[FI0][fj] = MFMA16(src[0], bf0[fj], acc[FI0][fj]);                  \
    _Pragma("unroll") for (int fj = 0; fj < 4; ++fj)                           \
        acc[(FI0) + 1][fj] = MFMA16(src[1], bf0[fj], acc[(FI0) + 1][fj]);      \
    _Pragma("unroll") for (int fj = 0; fj < 4; ++fj)                           \
        acc[FI0][fj] = MFMA16(src[2], bf1[fj], acc[FI0][fj]);                  \
    _Pragma("unroll") for (int fj = 0; fj < 4; ++fj)                           \
        acc[(FI0) + 1][fj] = MFMA16(src[3], bf1[fj], acc[(FI0) + 1][fj]);      \
    __builtin_amdgcn_s_setprio(0);                                             \
  }

#define PHASE_SYNC()                                                           \
  __builtin_amdgcn_s_barrier();                                                \
  asm volatile("s_waitcnt lgkmcnt(0)" ::: "memory");                           \
  __builtin_amdgcn_sched_barrier(0);

template <int EPI>
__global__ __launch_bounds__(512, 2) void gemm_kernel(
    const __hip_bfloat16* __restrict__ A, const __hip_bfloat16* __restrict__ Bt,
    const float* __restrict__ bias, const float* __restrict__ resid,
    void* __restrict__ outv, int M, int N, int K) {
  __shared__ __align__(16) unsigned char lds[2][65536];  // [dbuf][A 32K | B 32K]
  const int tid = threadIdx.x;
  const int lane = tid & 63, w = tid >> 6;  // 8 waves
  const int l15 = lane & 15, lg = lane >> 4;
  const int d = blockIdx.x;
  const int x = d & 7;   // XCD (round-robin dispatch)
  const int i = d >> 3;  // within-XCD index
  const int cC = (i & 7) + 8 * (i >> 5);
  const int rC = x + 8 * ((i >> 3) & 3);
  const int m0 = rC * 256, n0 = cC * 256;
  const int wm = (w >> 2) * 128, wn = (w & 3) * 64;

  f32x4 acc[8][4] = {};

  const int row8 = lane >> 3;        // 0..7 (row within 8-row chunk)
  const int g8 = (lane & 7) ^ row8;  // pre-swizzled source 16B-block
  const int wa = (w & 3) + ((w >> 2) * 16);  // A-chunk base for this wave

  auto stA = [&](int tt, int c) {
    GLOAD16(A + (size_t)(m0 + c * 8 + row8) * K + (size_t)tt * 64 + g8 * 8,
            lds[tt & 1] + c * 1024);
  };
  auto stB = [&](int tt, int c) {
    GLOAD16(Bt + (size_t)(n0 + c * 8 + row8) * K + (size_t)tt * 64 + g8 * 8,
            lds[tt & 1] + 32768 + c * 1024);
  };

  const int nt = K >> 6;  // K-tiles of 64 (nt >= 32 for all our GEMMs)

  // prologue: tile0 all 8 loads, tile1 first 7 (A-q3 of tile1 staged at t0.P0)
  stB(0, w); stB(0, 8 + w); stA(0, wa);
  stB(0, 16 + w); stB(0, 24 + w); stA(0, wa + 4);
  stA(0, wa + 8); stA(0, wa + 12);
  stB(1, w); stB(1, 8 + w); stA(1, wa);
  stB(1, 16 + w); stB(1, 24 + w); stA(1, wa + 4);
  stA(1, wa + 8);
  asm volatile("s_waitcnt vmcnt(7)" ::: "memory");  // tile0 fully in LDS
  __builtin_amdgcn_s_barrier();

  short8 afA[4], afB[4], bf0[4], bf1[4];
  READ_AF(afA, lds[0], 0)  // preread tile0 A-q0

  for (int t = 0; t < nt; ++t) {
    const unsigned char* db = lds[t & 1];
    const unsigned char* dbn = lds[(t + 1) & 1];
    const bool s1 = (t + 1 < nt), s2 = (t + 2 < nt);
    // ---------------- P0: bf reads + MFMA q0 (afA), issue q1 reads ----------
    if (s1) stA(t + 1, wa + 12);
#pragma unroll
    for (int f = 0; f < 4; ++f) {
      const int rb = wn + f * 16 + l15;
      bf0[f] = *(const short8*)(db + 32768 + rb * 128 + ((lg ^ (rb & 7)) << 4));
      bf1[f] =
          *(const short8*)(db + 32768 + rb * 128 + (((4 + lg) ^ (rb & 7)) << 4));
    }
    PHASE_SYNC()                 // afA(q0) + bf ready
    READ_AF(afB, db, 2)          // issue q1 reads (drain under MFMA)
    __builtin_amdgcn_sched_barrier(0);
    MFMA_BLOCK(afA, 0)
    __builtin_amdgcn_s_barrier();  // end P0: B + A-q0 of tile t dead
    // ---------------- P1: MFMA q1 (afB), issue q2 reads ----------
    if (s2) { stB(t + 2, w); stB(t + 2, 8 + w); stA(t + 2, wa); }
    PHASE_SYNC()
    READ_AF(afA, db, 4)
    __builtin_amdgcn_sched_barrier(0);
    MFMA_BLOCK(afB, 2)
    __builtin_amdgcn_s_barrier();  // end P1: A-q1 dead
    // ---------------- P2: MFMA q2 (afA), issue q3 reads; vmcnt here --------
    if (s2) { stB(t + 2, 16 + w); stB(t + 2, 24 + w); stA(t + 2, wa + 4); }
    PHASE_SYNC()
    READ_AF(afB, db, 6)
    __builtin_amdgcn_sched_barrier(0);
    MFMA_BLOCK(afA, 4)
    if (s1) {
      if (s2)
        asm volatile("s_waitcnt vmcnt(6)" ::: "memory");  // stage(t+1) landed
      else
        asm volatile("s_waitcnt vmcnt(0)" ::: "memory");
    }
    __builtin_amdgcn_s_barrier();  // end P2: certifies tile t+1 data in LDS
    // ---------------- P3: MFMA q3 (afB), preread t+1's q0 ----------
    if (s2) stA(t + 2, wa + 8);
    PHASE_SYNC()
    if (s1) READ_AF(afA, dbn, 0)   // preread tile t+1 A-q0 (safe post-P2)
    __builtin_amdgcn_sched_barrier(0);
    MFMA_BLOCK(afB, 6)
    __builtin_amdgcn_s_barrier();  // end P3: A-q3 dead
  }

#pragma unroll
  for (int fi = 0; fi < 8; ++fi) {
#pragma unroll
    for (int fj = 0; fj < 4; ++fj) {
      const int mb = m0 + wm + fi * 16 + lg * 4;
      const int n = n0 + wn + fj * 16 + l15;
      const float bv = bias ? bias[n] : 0.0f;
      if constexpr (EPI == EPI_VT) {
        // out bf16 [B][H][DK][SEQ]; m -> (b, s), n -> (h, d)
        const int bb = mb >> 11, ss = mb & (SEQ - 1);
        const int hh = n >> 7, dd = n & (DK - 1);
        short4v pk;
#pragma unroll
        for (int r = 0; r < 4; ++r) pk[r] = (short)f2bf(acc[fi][fj][r] + bv);
        __hip_bfloat16* o = (__hip_bfloat16*)outv;
        *(short4v*)(o + ((size_t)((bb * NUM_HEADS + hh) * DK + dd)) * SEQ + ss) = pk;
      } else {
#pragma unroll
        for (int r = 0; r < 4; ++r) {
          const int m = mb + r;
          const float v = acc[fi][fj][r] + bv;
          if constexpr (EPI == EPI_BF16) {
            ((__hip_bfloat16*)outv)[(size_t)m * N + n] = __float2bfloat16(v);
          } else if constexpr (EPI == EPI_GELU) {
            const float ge = 0.5f * v * (1.0f + erff(v * 0.70710678118654752f));
            ((__hip_bfloat16*)outv)[(size_t)m * N + n] = __float2bfloat16(ge);
          } else {  // EPI_RESID (resid may alias outv: same-element read->write)
            ((float*)outv)[(size_t)m * N + n] = resid[(size_t)m * N + n] + v;
          }
        }
      }
    }
  }
}

// ---------------------------------------------------------------------------
// Flash attention (causal). Grid: (SEQ/128, B*H). 8 waves, 16 q-rows each.
// LPT dispatch; dbuf K/V stage-ahead + counted vmcnt(4); bf16 P-scratch with
// conflict-reduced slot = ((tt>>3)+qq+(qq>>3))&7; defer-max; setprio. 80KB.
// ---------------------------------------------------------------------------
__global__ __launch_bounds__(512, 4) void attn_kernel(
    const __hip_bfloat16* __restrict__ Qm, const __hip_bfloat16* __restrict__ Km,
    const __hip_bfloat16* __restrict__ Vt, __hip_bfloat16* __restrict__ Om) {
  __shared__ __align__(16) unsigned char Kl[2][16384];  // [64 t][128 d] swizzled
  __shared__ __align__(16) unsigned char Vl[2][16384];  // [128 d][64 t] swizzled
  __shared__ __align__(16) unsigned char Pl[16384];     // per-wave 2KB bf16 [16 q][64 t]
  const int tid = threadIdx.x;
  const int lane = tid & 63, w = tid >> 6;  // w in 0..7
  const int l15 = lane & 15, lg = lane >> 4;
  const int bh = blockIdx.y, b = bh >> 4, h = bh & 15;
  const int q0 = ((int)gridDim.x - 1 - (int)blockIdx.x) * 128;  // LPT order
  const int qw = q0 + w * 16;
  const int row8 = lane >> 3;
  const int nt = (q0 >> 6) + 2;  // K/V tiles 0 .. q0/64+1

  // Q fragments (A-operand): row = l15, k = ks*32 + lg*8 .. +8
  short8 qf[4];
  const __hip_bfloat16* qbase = Qm + (size_t)(b * SEQ + qw + l15) * D_MODEL + h * DK;
#pragma unroll
  for (int ks = 0; ks < 4; ++ks) qf[ks] = *(const short8*)(qbase + ks * 32 + lg * 8);

  float m_run[4], l_run[4];
  f32x4 acc_o[8];
#pragma unroll
  for (int r = 0; r < 4; ++r) { m_run[r] = -1e30f; l_run[r] = 0.0f; }
#pragma unroll
  for (int fd = 0; fd < 8; ++fd) acc_o[fd] = (f32x4){0.f, 0.f, 0.f, 0.f};

  auto STAGE = [&](int tt) {
    unsigned char* kb = Kl[tt & 1];
    unsigned char* vb = Vl[tt & 1];
    const int t0 = tt * 64;
#pragma unroll
    for (int i = 0; i < 2; ++i) {
      const int c = w * 2 + i;
      const int row = c * 4 + lg;
      const int gcb = l15 ^ (row & 7);
      GLOAD16(Km + (size_t)(b * SEQ + t0 + row) * D_MODEL + h * DK + gcb * 8,
              kb + c * 1024);
    }
#pragma unroll
    for (int i = 0; i < 2; ++i) {
      const int c = w * 2 + i;
      const int row = c * 8 + row8;
      const int gcb = (lane & 7) ^ (row & 7);
      GLOAD16(Vt + (size_t)(bh * DK + row) * SEQ + t0 + gcb * 8, vb + c * 1024);
    }
  };

  STAGE(0);
  for (int t = 0; t < nt; ++t) {
    const int t0 = t * 64;
    if (t + 1 < nt) {
      STAGE(t + 1);  // 4 loads -> in flight across this tile's compute
      asm volatile("s_waitcnt vmcnt(4)" ::: "memory");  // tile t complete
    } else {
      asm volatile("s_waitcnt vmcnt(0)" ::: "memory");
    }
    __builtin_amdgcn_s_barrier();  // all waves: tile t in LDS; t-1 reads done
    asm volatile("" ::: "memory");
    if (t0 <= qw + 15) {
      const unsigned char* kb = Kl[t & 1];
      const unsigned char* vb = Vl[t & 1];
      // S = Q K^T  (output: row q = lg*4+r, col key = l15 within frag fn)
      f32x4 sacc[4];
#pragma unroll
      for (int fn = 0; fn < 4; ++fn) sacc[fn] = (f32x4){0.f, 0.f, 0.f, 0.f};
      __builtin_amdgcn_s_setprio(1);
#pragma unroll
      for (int ks = 0; ks < 4; ++ks) {
        const int cb = ks * 4 + lg;
#pragma unroll
        for (int fn = 0; fn < 4; ++fn) {
          const int rn = fn * 16 + l15;
          short8 kf = *(const short8*)(kb + rn * 256 + ((cb ^ (rn & 7)) << 4));
          sacc[fn] = MFMA16(qf[ks], kf, sacc[fn]);
        }
      }
      __builtin_amdgcn_s_setprio(0);
      const float scale = 0.088388347648318447f;  // 1/sqrt(128)
      float mt[4] = {-1e30f, -1e30f, -1e30f, -1e30f};
#pragma unroll
      for (int fn = 0; fn < 4; ++fn) {
        const int key = t0 + fn * 16 + l15;
#pragma unroll
        for (int r = 0; r < 4; ++r) {
          const int qg = qw + lg * 4 + r;
          float sv = sacc[fn][r] * scale;
          sv = (key <= qg) ? sv : -1e30f;
          sacc[fn][r] = sv;
          mt[r] = fmaxf(mt[r], sv);
        }
      }
#pragma unroll
      for (int r = 0; r < 4; ++r)
#pragma unroll
        for (int off = 1; off < 16; off <<= 1) mt[r] = fmaxf(mt[r], __shfl_xor(mt[r], off));
      // defer-max (T13): skip rescale when tile max is within THR of running max
      int ok = 1;
#pragma unroll
      for (int r = 0; r < 4; ++r) ok = ok && (mt[r] <= m_run[r] + 8.0f);
      const bool defer = __all(ok);
      float alpha[4];
      if (!defer) {
#pragma unroll
        for (int r = 0; r < 4; ++r) {
          const float mnew = fmaxf(m_run[r], mt[r]);
          alpha[r] = __expf(m_run[r] - mnew);
          m_run[r] = mnew;
        }
      }
      float ls[4] = {0.f, 0.f, 0.f, 0.f};
#pragma unroll
      for (int fn = 0; fn < 4; ++fn)
#pragma unroll
        for (int r = 0; r < 4; ++r) {
          const float p = __expf(sacc[fn][r] - m_run[r]);
          sacc[fn][r] = p;
          ls[r] += p;
        }
#pragma unroll
      for (int r = 0; r < 4; ++r) {
#pragma unroll
        for (int off = 1; off < 16; off <<= 1) ls[r] += __shfl_xor(ls[r], off);
        l_run[r] = (defer ? l_run[r] : l_run[r] * alpha[r]) + ls[r];
      }
      if (!defer) {
#pragma unroll
        for (int fd = 0; fd < 8; ++fd)
#pragma unroll
          for (int r = 0; r < 4; ++r) acc_o[fd][r] *= alpha[r];
      }
      // write P (bf16): row q (128B), slot = ((tt>>3)+qq+(qq>>3))&7 (2-4 way)
      unsigned char* pw = Pl + w * 2048;
#pragma unroll
      for (int fn = 0; fn < 4; ++fn) {
        const int tt = fn * 16 + l15;
#pragma unroll
        for (int r = 0; r < 4; ++r) {
          const int qq = lg * 4 + r;
          *(unsigned short*)(pw + qq * 128 +
                             ((((tt >> 3) + qq + (qq >> 3)) & 7) << 4) +
                             (tt & 7) * 2) = f2bf(sacc[fn][r]);
        }
      }
      // O += P V  (A-operand P: row q = l15, k-slot tb = ks*4+lg)
#pragma unroll
      for (int ks = 0; ks < 2; ++ks) {
        const int tb = ks * 4 + lg;
        short8 pf = *(const short8*)(Pl + w * 2048 + l15 * 128 +
                                     (((tb + l15 + (l15 >> 3)) & 7) << 4));
        const int cb = ks * 4 + lg;
        __builtin_amdgcn_s_setprio(1);
#pragma unroll
        for (int fd = 0; fd < 8; ++fd) {
          const int rv = fd * 16 + l15;
          short8 vf = *(const short8*)(vb + rv * 128 + ((cb ^ (rv & 7)) << 4));
          acc_o[fd] = MFMA16(pf, vf, acc_o[fd]);
        }
        __builtin_amdgcn_s_setprio(0);
      }
    }
    asm volatile("" ::: "memory");
    __builtin_amdgcn_s_barrier();  // all reads of buf[t&1] done before t+2 stages it
    asm volatile("" ::: "memory");
  }
#pragma unroll
  for (int r = 0; r < 4; ++r) {
    const float inv = 1.0f / l_run[r];
    const int qg = qw + lg * 4 + r;
    __hip_bfloat16* ob = Om + (size_t)(b * SEQ + qg) * D_MODEL + h * DK + l15;
#pragma unroll
    for (int fd = 0; fd < 8; ++fd)
      ob[fd * 16] = __float2bfloat16(acc_o[fd][r] * inv);
  }
}

// ---------------------------------------------------------------------------
// Workspace layout (192 MiB peak, time-shared):
//   @0   Hb (32M)  LN1 out -> later LN2 out
//   @32  Qb (32M) -\
//   @64  Kb (32M)  |-> after O-proj: FF1 full tensor (128M, 8192x8192 bf16)
//   @96  Vt (32M)  |
//   @128 AO (32M) -/
//   @160 WqT/WkT/WvT/WoT (4x8M) -> after O-proj: W1T (32M) -> after FF1: W2T (32M)
// X2 (f32 residual stream) lives in d_out itself.
// ---------------------------------------------------------------------------
extern "C" void kernel_launch(void* const* d_in, const int* in_sizes, int n_in,
                              void* d_out, int out_size, void* d_ws, size_t ws_size,
                              hipStream_t stream) {
  (void)in_sizes; (void)n_in; (void)out_size;
  const size_t MB = 1024 * 1024;
  if (ws_size < 192 * MB) return;  // diagnostic guard

  const float* x  = (const float*)d_in[0];
  const float* Wq = (const float*)d_in[1];
  const float* bq = (const float*)d_in[2];
  const float* Wk = (const float*)d_in[3];
  const float* bk = (const float*)d_in[4];
  const float* Wv = (const float*)d_in[5];
  const float* bv = (const float*)d_in[6];
  const float* Wo = (const float*)d_in[7];
  const float* bo = (const float*)d_in[8];
  const float* W1 = (const float*)d_in[9];
  const float* b1 = (const float*)d_in[10];
  const float* W2 = (const float*)d_in[11];
  const float* b2 = (const float*)d_in[12];
  const float* g1 = (const float*)d_in[13];
  const float* be1 = (const float*)d_in[14];
  const float* g2 = (const float*)d_in[15];
  const float* be2 = (const float*)d_in[16];

  char* ws = (char*)d_ws;
  __hip_bfloat16* Hb  = (__hip_bfloat16*)(ws + 0 * MB);
  __hip_bfloat16* Qb  = (__hip_bfloat16*)(ws + 32 * MB);
  __hip_bfloat16* Kb  = (__hip_bfloat16*)(ws + 64 * MB);
  __hip_bfloat16* Vtb = (__hip_bfloat16*)(ws + 96 * MB);
  __hip_bfloat16* AOb = (__hip_bfloat16*)(ws + 128 * MB);
  __hip_bfloat16* FF1 = (__hip_bfloat16*)(ws + 32 * MB);   // after O-proj, 128M
  __hip_bfloat16* WqT = (__hip_bfloat16*)(ws + 160 * MB);
  __hip_bfloat16* WkT = (__hip_bfloat16*)(ws + 168 * MB);
  __hip_bfloat16* WvT = (__hip_bfloat16*)(ws + 176 * MB);
  __hip_bfloat16* WoT = (__hip_bfloat16*)(ws + 184 * MB);
  __hip_bfloat16* W1T = (__hip_bfloat16*)(ws + 160 * MB);  // after O-proj
  __hip_bfloat16* W2T = (__hip_bfloat16*)(ws + 160 * MB);  // after FF1
  float* X2 = (float*)d_out;  // residual stream lives in d_out

  const dim3 tb(256);
  transpose_cvt_kernel<<<dim3(64, 64), tb, 0, stream>>>(Wq, WqT, 2048, 2048);
  transpose_cvt_kernel<<<dim3(64, 64), tb, 0, stream>>>(Wk, WkT, 2048, 2048);
  transpose_cvt_kernel<<<dim3(64, 64), tb, 0, stream>>>(Wv, WvT, 2048, 2048);
  transpose_cvt_kernel<<<dim3(64, 64), tb, 0, stream>>>(Wo, WoT, 2048, 2048);

  layernorm_kernel<<<MTOT, tb, 0, stream>>>(x, g1, be1, Hb);

  // QKV/O-proj: M=8192, N=2048 -> 256 blocks (XCD window 4r x 8c)
  gemm_kernel<EPI_BF16><<<256, 512, 0, stream>>>(Hb, WqT, bq, nullptr, Qb, MTOT, 2048, 2048);
  gemm_kernel<EPI_BF16><<<256, 512, 0, stream>>>(Hb, WkT, bk, nullptr, Kb, MTOT, 2048, 2048);
  gemm_kernel<EPI_VT><<<256, 512, 0, stream>>>(Hb, WvT, bv, nullptr, Vtb, MTOT, 2048, 2048);

  attn_kernel<<<dim3(SEQ / 128, BATCH * NUM_HEADS), dim3(512), 0, stream>>>(Qb, Kb, Vtb, AOb);

  gemm_kernel<EPI_RESID><<<256, 512, 0, stream>>>(AOb, WoT, bo, x, X2, MTOT, 2048, 2048);

  layernorm_kernel<<<MTOT, tb, 0, stream>>>(X2, g2, be2, Hb);

  // FFN full-M: W1T into dead small-weight region, FF1 into dead Q/K/Vt/AO
  transpose_cvt_kernel<<<dim3(256, 64), tb, 0, stream>>>(W1, W1T, 2048, 8192);
  // FF1: M=8192, N=8192 -> 1024 blocks
  gemm_kernel<EPI_GELU><<<1024, 512, 0, stream>>>(Hb, W1T, b1, nullptr, FF1, MTOT, 8192, 2048);
  // W2T overwrites W1T (dead after FF1)
  transpose_cvt_kernel<<<dim3(64, 256), tb, 0, stream>>>(W2, W2T, 8192, 2048);
  // FF2: M=8192, N=2048, K=8192 -> 256 blocks
  gemm_kernel<EPI_RESID><<<256, 512, 0, stream>>>(FF1, W2T, b2, X2, X2, MTOT, 2048, 8192);
}

// Round 13
// 1189.956 us; speedup vs baseline: 1.0587x; 1.0587x over previous
//
#include <hip/hip_runtime.h>
#include <hip/hip_bf16.h>

#define D_MODEL 2048
#define NUM_HEADS 16
#define D_FF 8192
#define BATCH 4
#define SEQ 2048
#define DK 128
#define MTOT (BATCH * SEQ)  // 8192

typedef __attribute__((ext_vector_type(8))) short short8;
typedef __attribute__((ext_vector_type(4))) short short4v;
typedef __attribute__((ext_vector_type(4))) float f32x4;

#define MFMA16(a, b, c) __builtin_amdgcn_mfma_f32_16x16x32_bf16(a, b, c, 0, 0, 0)

#define GLOAD16(gp, lp)                                                        \
  __builtin_amdgcn_global_load_lds(                                            \
      (const __attribute__((address_space(1))) void*)(gp),                     \
      (__attribute__((address_space(3))) void*)(lp), 16, 0, 0)

static __device__ __forceinline__ unsigned short f2bf(float f) {
  return __builtin_bit_cast(unsigned short, __float2bfloat16(f));
}

// ---------------------------------------------------------------------------
// Weight convert + transpose: in f32 [K][N] -> out bf16 [N][K]
// ---------------------------------------------------------------------------
__global__ __launch_bounds__(256) void transpose_cvt_kernel(
    const float* __restrict__ in, __hip_bfloat16* __restrict__ out, int K, int N) {
  __shared__ float tile[32][33];
  const int n0 = blockIdx.x * 32, k0 = blockIdx.y * 32;
  const int tx = threadIdx.x & 31, ty = threadIdx.x >> 5;  // 32 x 8
#pragma unroll
  for (int i = 0; i < 4; ++i)
    tile[ty + i * 8][tx] = in[(size_t)(k0 + ty + i * 8) * N + n0 + tx];
  __syncthreads();
#pragma unroll
  for (int i = 0; i < 4; ++i)
    out[(size_t)(n0 + ty + i * 8) * K + k0 + tx] = __float2bfloat16(tile[tx][ty + i * 8]);
}

// ---------------------------------------------------------------------------
// LayerNorm: f32 [M][D_MODEL] -> bf16 [M][D_MODEL]
// ---------------------------------------------------------------------------
__global__ __launch_bounds__(256) void layernorm_kernel(
    const float* __restrict__ x, const float* __restrict__ g,
    const float* __restrict__ bta, __hip_bfloat16* __restrict__ out) {
  const int row = blockIdx.x;
  const int tid = threadIdx.x;
  const float* xr = x + (size_t)row * D_MODEL;
  float4 v0 = *(const float4*)(xr + tid * 8);
  float4 v1 = *(const float4*)(xr + tid * 8 + 4);
  float s = v0.x + v0.y + v0.z + v0.w + v1.x + v1.y + v1.z + v1.w;
  float q = v0.x * v0.x + v0.y * v0.y + v0.z * v0.z + v0.w * v0.w +
            v1.x * v1.x + v1.y * v1.y + v1.z * v1.z + v1.w * v1.w;
#pragma unroll
  for (int off = 1; off < 64; off <<= 1) {
    s += __shfl_xor(s, off);
    q += __shfl_xor(q, off);
  }
  __shared__ float rs[4], rq[4];
  if ((tid & 63) == 0) {
    rs[tid >> 6] = s;
    rq[tid >> 6] = q;
  }
  __syncthreads();
  s = rs[0] + rs[1] + rs[2] + rs[3];
  q = rq[0] + rq[1] + rq[2] + rq[3];
  const float mu = s * (1.0f / D_MODEL);
  const float var = q * (1.0f / D_MODEL) - mu * mu;
  const float rstd = rsqrtf(var + 1e-5f);
  float4 g0 = *(const float4*)(g + tid * 8);
  float4 g1 = *(const float4*)(g + tid * 8 + 4);
  float4 b0 = *(const float4*)(bta + tid * 8);
  float4 b1 = *(const float4*)(bta + tid * 8 + 4);
  short8 o;
  o[0] = (short)f2bf((v0.x - mu) * rstd * g0.x + b0.x);
  o[1] = (short)f2bf((v0.y - mu) * rstd * g0.y + b0.y);
  o[2] = (short)f2bf((v0.z - mu) * rstd * g0.z + b0.z);
  o[3] = (short)f2bf((v0.w - mu) * rstd * g0.w + b0.w);
  o[4] = (short)f2bf((v1.x - mu) * rstd * g1.x + b1.x);
  o[5] = (short)f2bf((v1.y - mu) * rstd * g1.y + b1.y);
  o[6] = (short)f2bf((v1.z - mu) * rstd * g1.z + b1.z);
  o[7] = (short)f2bf((v1.w - mu) * rstd * g1.w + b1.w);
  *(short8*)(out + (size_t)row * D_MODEL + tid * 8) = o;
}

// ---------------------------------------------------------------------------
// GEMM v5 (round-11 best): 256x256 tile, BK=64, 8 waves (2Mx4N), dbuf LDS.
// 4 phases/K-tile: {stage / ds_read / barrier / lgkmcnt(0) / 16 MFMA /
// barrier}; single vmcnt(7) at P3 (counted, never drained mid-loop).
// XCD decode: 4r x 8c concurrent window per XCD.
// ---------------------------------------------------------------------------
enum { EPI_BF16 = 0, EPI_VT = 1, EPI_RESID = 2, EPI_GELU = 3 };

#define AF_MFMA_PHASE(FI0)                                                     \
  {                                                                            \
    const int raA = wm + (FI0) * 16 + l15;                                     \
    const int raB = wm + ((FI0) + 1) * 16 + l15;                               \
    short8 aA0 = *(const short8*)(db + raA * 128 + ((lg ^ (raA & 7)) << 4));   \
    short8 aB0 = *(const short8*)(db + raB * 128 + ((lg ^ (raB & 7)) << 4));   \
    short8 aA1 =                                                               \
        *(const short8*)(db + raA * 128 + (((4 + lg) ^ (raA & 7)) << 4));      \
    short8 aB1 =                                                               \
        *(const short8*)(db + raB * 128 + (((4 + lg) ^ (raB & 7)) << 4));      \
    __builtin_amdgcn_s_barrier();                                              \
    asm volatile("s_waitcnt lgkmcnt(0)" ::: "memory");                         \
    __builtin_amdgcn_sched_barrier(0);                                         \
    __builtin_amdgcn_s_setprio(1);                                             \
    _Pragma("unroll") for (int fj = 0; fj < 4; ++fj)                           \
        acc[FI0][fj] = MFMA16(aA0, bf0[fj], acc[FI0][fj]);                     \
    _Pragma("unroll") for (int fj = 0; fj < 4; ++fj)                           \
        acc[(FI0) + 1][fj] = MFMA16(aB0, bf0[fj], acc[(FI0) + 1][fj]);         \
    _Pragma("unroll") for (int fj = 0; fj < 4; ++fj)                           \
        acc[FI0][fj] = MFMA16(aA1, bf1[fj], acc[FI0][fj]);                     \
    _Pragma("unroll") for (int fj = 0; fj < 4; ++fj)                           \
        acc[(FI0) + 1][fj] = MFMA16(aB1, bf1[fj], acc[(FI0) + 1][fj]);         \
    __builtin_amdgcn_s_setprio(0);                                             \
  }

template <int EPI>
__global__ __launch_bounds__(512, 2) void gemm_kernel(
    const __hip_bfloat16* __restrict__ A, const __hip_bfloat16* __restrict__ Bt,
    const float* __restrict__ bias, const float* __restrict__ resid,
    void* __restrict__ outv, int M, int N, int K) {
  __shared__ __align__(16) unsigned char lds[2][65536];  // [dbuf][A 32K | B 32K]
  const int tid = threadIdx.x;
  const int lane = tid & 63, w = tid >> 6;  // 8 waves
  const int l15 = lane & 15, lg = lane >> 4;
  const int d = blockIdx.x;
  const int x = d & 7;   // XCD (round-robin dispatch)
  const int i = d >> 3;  // within-XCD index
  const int cC = (i & 7) + 8 * (i >> 5);
  const int rC = x + 8 * ((i >> 3) & 3);
  const int m0 = rC * 256, n0 = cC * 256;
  const int wm = (w >> 2) * 128, wn = (w & 3) * 64;

  f32x4 acc[8][4] = {};

  const int row8 = lane >> 3;        // 0..7 (row within 8-row chunk)
  const int g8 = (lane & 7) ^ row8;  // pre-swizzled source 16B-block
  const int wa = (w & 3) + ((w >> 2) * 16);  // A-chunk base for this wave

  auto stA = [&](int tt, int c) {
    GLOAD16(A + (size_t)(m0 + c * 8 + row8) * K + (size_t)tt * 64 + g8 * 8,
            lds[tt & 1] + c * 1024);
  };
  auto stB = [&](int tt, int c) {
    GLOAD16(Bt + (size_t)(n0 + c * 8 + row8) * K + (size_t)tt * 64 + g8 * 8,
            lds[tt & 1] + 32768 + c * 1024);
  };

  const int nt = K >> 6;  // K-tiles of 64

  // prologue: tile0 all 8 loads, tile1 first 7 (A-q3 of tile1 staged at t0.P0)
  stB(0, w); stB(0, 8 + w); stA(0, wa);
  stB(0, 16 + w); stB(0, 24 + w); stA(0, wa + 4);
  stA(0, wa + 8); stA(0, wa + 12);
  stB(1, w); stB(1, 8 + w); stA(1, wa);
  stB(1, 16 + w); stB(1, 24 + w); stA(1, wa + 4);
  stA(1, wa + 8);
  asm volatile("s_waitcnt vmcnt(7)" ::: "memory");  // tile0 fully in LDS
  __builtin_amdgcn_s_barrier();

  for (int t = 0; t < nt; ++t) {
    const unsigned char* db = lds[t & 1];
    const bool s1 = (t + 1 < nt), s2 = (t + 2 < nt);
    short8 bf0[4], bf1[4];
    // ---------------- P0: bf(all) + af fi0,1 ----------------
    if (s1) stA(t + 1, wa + 12);  // A-q3 of t+1 (dead since (t-1).P3)
#pragma unroll
    for (int f = 0; f < 4; ++f) {
      const int rb = wn + f * 16 + l15;
      bf0[f] = *(const short8*)(db + 32768 + rb * 128 + ((lg ^ (rb & 7)) << 4));
      bf1[f] =
          *(const short8*)(db + 32768 + rb * 128 + (((4 + lg) ^ (rb & 7)) << 4));
    }
    AF_MFMA_PHASE(0)
    __builtin_amdgcn_s_barrier();  // end P0: B + A-q0 of tile t dead
    // ---------------- P1: af fi2,3 ----------------
    if (s2) { stB(t + 2, w); stB(t + 2, 8 + w); stA(t + 2, wa); }
    AF_MFMA_PHASE(2)
    __builtin_amdgcn_s_barrier();  // end P1: A-q1 dead
    // ---------------- P2: af fi4,5 ----------------
    if (s2) { stB(t + 2, 16 + w); stB(t + 2, 24 + w); stA(t + 2, wa + 4); }
    AF_MFMA_PHASE(4)
    __builtin_amdgcn_s_barrier();  // end P2: A-q2 dead
    // ---------------- P3: af fi6,7 ----------------
    if (s2) stA(t + 2, wa + 8);
    AF_MFMA_PHASE(6)
    if (s2)
      asm volatile("s_waitcnt vmcnt(7)" ::: "memory");  // t+1's 8 retired
    else
      asm volatile("s_waitcnt vmcnt(0)" ::: "memory");
    __builtin_amdgcn_s_barrier();  // end P3: next tile's reads now safe
  }

#pragma unroll
  for (int fi = 0; fi < 8; ++fi) {
#pragma unroll
    for (int fj = 0; fj < 4; ++fj) {
      const int mb = m0 + wm + fi * 16 + lg * 4;
      const int n = n0 + wn + fj * 16 + l15;
      const float bv = bias ? bias[n] : 0.0f;
      if constexpr (EPI == EPI_VT) {
        // out bf16 [B][H][DK][SEQ]; m -> (b, s), n -> (h, d)
        const int bb = mb >> 11, ss = mb & (SEQ - 1);
        const int hh = n >> 7, dd = n & (DK - 1);
        short4v pk;
#pragma unroll
        for (int r = 0; r < 4; ++r) pk[r] = (short)f2bf(acc[fi][fj][r] + bv);
        __hip_bfloat16* o = (__hip_bfloat16*)outv;
        *(short4v*)(o + ((size_t)((bb * NUM_HEADS + hh) * DK + dd)) * SEQ + ss) = pk;
      } else {
#pragma unroll
        for (int r = 0; r < 4; ++r) {
          const int m = mb + r;
          const float v = acc[fi][fj][r] + bv;
          if constexpr (EPI == EPI_BF16) {
            ((__hip_bfloat16*)outv)[(size_t)m * N + n] = __float2bfloat16(v);
          } else if constexpr (EPI == EPI_GELU) {
            const float ge = 0.5f * v * (1.0f + erff(v * 0.70710678118654752f));
            ((__hip_bfloat16*)outv)[(size_t)m * N + n] = __float2bfloat16(ge);
          } else {  // EPI_RESID (resid may alias outv: same-element read->write)
            ((float*)outv)[(size_t)m * N + n] = resid[(size_t)m * N + n] + v;
          }
        }
      }
    }
  }
}

// ---------------------------------------------------------------------------
// Flash attention (causal), swapped-QK^T in-register softmax.
// Grid: (SEQ/128, B*H). 8 waves, 16 q-rows each. S = mfma(K, Q) puts a full
// P-row (16 keys) per lane for q = lane&15: softmax = per-lane scalar + 2
// shfl_xor; P reaches PV's A-operand via 32 shfl + select + cvt (no P-LDS).
// LDS 64KB (2 blocks/CU). Dbuf K/V stage-ahead + counted vmcnt(4); LPT;
// defer-max; setprio.
// ---------------------------------------------------------------------------
__global__ __launch_bounds__(512, 4) void attn_kernel(
    const __hip_bfloat16* __restrict__ Qm, const __hip_bfloat16* __restrict__ Km,
    const __hip_bfloat16* __restrict__ Vt, __hip_bfloat16* __restrict__ Om) {
  __shared__ __align__(16) unsigned char Kl[2][16384];  // [64 t][128 d] swizzled
  __shared__ __align__(16) unsigned char Vl[2][16384];  // [128 d][64 t] swizzled
  const int tid = threadIdx.x;
  const int lane = tid & 63, w = tid >> 6;  // w in 0..7
  const int l15 = lane & 15, lg = lane >> 4;
  const int bh = blockIdx.y, b = bh >> 4, h = bh & 15;
  const int q0 = ((int)gridDim.x - 1 - (int)blockIdx.x) * 128;  // LPT order
  const int qw = q0 + w * 16;
  const int row8 = lane >> 3;
  const int nt = (q0 >> 6) + 2;  // K/V tiles 0 .. q0/64+1

  // Q fragments: row/col = l15 (A and B layouts coincide), k = ks*32 + lg*8
  short8 qf[4];
  const __hip_bfloat16* qbase = Qm + (size_t)(b * SEQ + qw + l15) * D_MODEL + h * DK;
#pragma unroll
  for (int ks = 0; ks < 4; ++ks) qf[ks] = *(const short8*)(qbase + ks * 32 + lg * 8);

  float m_run = -1e30f, l_run = 0.0f;  // stats for q = qw + l15 (x4 replicas)
  f32x4 acc_o[8];
#pragma unroll
  for (int fd = 0; fd < 8; ++fd) acc_o[fd] = (f32x4){0.f, 0.f, 0.f, 0.f};

  auto STAGE = [&](int tt) {
    unsigned char* kb = Kl[tt & 1];
    unsigned char* vb = Vl[tt & 1];
    const int t0s = tt * 64;
#pragma unroll
    for (int i = 0; i < 2; ++i) {
      const int c = w * 2 + i;
      const int row = c * 4 + lg;
      const int gcb = l15 ^ (row & 7);
      GLOAD16(Km + (size_t)(b * SEQ + t0s + row) * D_MODEL + h * DK + gcb * 8,
              kb + c * 1024);
    }
#pragma unroll
    for (int i = 0; i < 2; ++i) {
      const int c = w * 2 + i;
      const int row = c * 8 + row8;
      const int gcb = (lane & 7) ^ (row & 7);
      GLOAD16(Vt + (size_t)(bh * DK + row) * SEQ + t0s + gcb * 8, vb + c * 1024);
    }
  };

  STAGE(0);
  for (int t = 0; t < nt; ++t) {
    const int t0 = t * 64;
    if (t + 1 < nt) {
      STAGE(t + 1);  // 4 loads -> in flight across this tile's compute
      asm volatile("s_waitcnt vmcnt(4)" ::: "memory");  // tile t complete
    } else {
      asm volatile("s_waitcnt vmcnt(0)" ::: "memory");
    }
    __builtin_amdgcn_s_barrier();  // all waves: tile t in LDS; t-1 reads done
    asm volatile("" ::: "memory");
    if (t0 <= qw + 15) {
      const unsigned char* kb = Kl[t & 1];
      const unsigned char* vb = Vl[t & 1];
      // S^T = K Q : lane (l15, lg) gets P[q=qw+l15][key = t0+fn*16+lg*4+r]
      f32x4 sacc[4];
#pragma unroll
      for (int fn = 0; fn < 4; ++fn) sacc[fn] = (f32x4){0.f, 0.f, 0.f, 0.f};
      __builtin_amdgcn_s_setprio(1);
#pragma unroll
      for (int ks = 0; ks < 4; ++ks) {
        const int cb = ks * 4 + lg;
#pragma unroll
        for (int fn = 0; fn < 4; ++fn) {
          const int rn = fn * 16 + l15;
          short8 kf = *(const short8*)(kb + rn * 256 + ((cb ^ (rn & 7)) << 4));
          sacc[fn] = MFMA16(kf, qf[ks], sacc[fn]);  // swapped operands
        }
      }
      __builtin_amdgcn_s_setprio(0);
      const float scale = 0.088388347648318447f;  // 1/sqrt(128)
      const int qg = qw + l15;
      float mt = -1e30f;
#pragma unroll
      for (int fn = 0; fn < 4; ++fn) {
        const int keyb = t0 + fn * 16 + lg * 4;
#pragma unroll
        for (int r = 0; r < 4; ++r) {
          float sv = sacc[fn][r] * scale;
          sv = (keyb + r <= qg) ? sv : -1e30f;
          sacc[fn][r] = sv;
          mt = fmaxf(mt, sv);
        }
      }
      mt = fmaxf(mt, __shfl_xor(mt, 16));
      mt = fmaxf(mt, __shfl_xor(mt, 32));
      // defer-max (T13)
      const bool defer = __all(mt <= m_run + 8.0f);
      float alpha = 1.0f;
      if (!defer) {
        const float mnew = fmaxf(m_run, mt);
        alpha = __expf(m_run - mnew);
        m_run = mnew;
      }
      float ls = 0.0f;
#pragma unroll
      for (int fn = 0; fn < 4; ++fn)
#pragma unroll
        for (int r = 0; r < 4; ++r) {
          const float p = __expf(sacc[fn][r] - m_run);
          sacc[fn][r] = p;
          ls += p;
        }
      ls += __shfl_xor(ls, 16);
      ls += __shfl_xor(ls, 32);
      l_run = (defer ? l_run : l_run * alpha) + ls;
      if (!defer) {
        float abr[4];
#pragma unroll
        for (int r = 0; r < 4; ++r) abr[r] = __shfl(alpha, lg * 4 + r);
#pragma unroll
        for (int fd = 0; fd < 8; ++fd)
#pragma unroll
          for (int r = 0; r < 4; ++r) acc_o[fd][r] *= abr[r];
      }
      // P pack: pf[j] = P[q=l15][t = s*32 + lg*8 + j] via shfl+select
      const int srcLo = l15 + 16 * (2 * (lg & 1));
      const int srcHi = srcLo + 16;
      const int hi = lg >> 1;
#pragma unroll
      for (int s = 0; s < 2; ++s) {
        short8 pf;
#pragma unroll
        for (int j = 0; j < 4; ++j) {
          const float v0 = __shfl(sacc[2 * s][j], srcLo);
          const float v1 = __shfl(sacc[2 * s + 1][j], srcLo);
          pf[j] = (short)f2bf(hi ? v1 : v0);
          const float w0 = __shfl(sacc[2 * s][j], srcHi);
          const float w1 = __shfl(sacc[2 * s + 1][j], srcHi);
          pf[4 + j] = (short)f2bf(hi ? w1 : w0);
        }
        const int cb = s * 4 + lg;
        __builtin_amdgcn_s_setprio(1);
#pragma unroll
        for (int fd = 0; fd < 8; ++fd) {
          const int rv = fd * 16 + l15;
          short8 vf = *(const short8*)(vb + rv * 128 + ((cb ^ (rv & 7)) << 4));
          acc_o[fd] = MFMA16(pf, vf, acc_o[fd]);
        }
        __builtin_amdgcn_s_setprio(0);
      }
    }
    asm volatile("" ::: "memory");
    __builtin_amdgcn_s_barrier();  // all reads of buf[t&1] done before t+2 stages it
    asm volatile("" ::: "memory");
  }
  // epilogue: q = qw + lg*4 + r, d = fd*16 + l15
  float linv[4];
#pragma unroll
  for (int r = 0; r < 4; ++r) linv[r] = __shfl(l_run, lg * 4 + r);
#pragma unroll
  for (int r = 0; r < 4; ++r) {
    const float inv = 1.0f / linv[r];
    const int qg = qw + lg * 4 + r;
    __hip_bfloat16* ob = Om + (size_t)(b * SEQ + qg) * D_MODEL + h * DK + l15;
#pragma unroll
    for (int fd = 0; fd < 8; ++fd)
      ob[fd * 16] = __float2bfloat16(acc_o[fd][r] * inv);
  }
}

// ---------------------------------------------------------------------------
// Workspace layout (192 MiB peak, time-shared):
//   @0   Hb (32M)  LN1 out -> later LN2 out
//   @32  Qb (32M) -\
//   @64  Kb (32M)  |-> after O-proj: FF1 full tensor (128M, 8192x8192 bf16)
//   @96  Vt (32M)  |
//   @128 AO (32M) -/
//   @160 WqT/WkT/WvT/WoT (4x8M) -> after O-proj: W1T (32M) -> after FF1: W2T (32M)
// X2 (f32 residual stream) lives in d_out itself.
// ---------------------------------------------------------------------------
extern "C" void kernel_launch(void* const* d_in, const int* in_sizes, int n_in,
                              void* d_out, int out_size, void* d_ws, size_t ws_size,
                              hipStream_t stream) {
  (void)in_sizes; (void)n_in; (void)out_size;
  const size_t MB = 1024 * 1024;
  if (ws_size < 192 * MB) return;  // diagnostic guard

  const float* x  = (const float*)d_in[0];
  const float* Wq = (const float*)d_in[1];
  const float* bq = (const float*)d_in[2];
  const float* Wk = (const float*)d_in[3];
  const float* bk = (const float*)d_in[4];
  const float* Wv = (const float*)d_in[5];
  const float* bv = (const float*)d_in[6];
  const float* Wo = (const float*)d_in[7];
  const float* bo = (const float*)d_in[8];
  const float* W1 = (const float*)d_in[9];
  const float* b1 = (const float*)d_in[10];
  const float* W2 = (const float*)d_in[11];
  const float* b2 = (const float*)d_in[12];
  const float* g1 = (const float*)d_in[13];
  const float* be1 = (const float*)d_in[14];
  const float* g2 = (const float*)d_in[15];
  const float* be2 = (const float*)d_in[16];

  char* ws = (char*)d_ws;
  __hip_bfloat16* Hb  = (__hip_bfloat16*)(ws + 0 * MB);
  __hip_bfloat16* Qb  = (__hip_bfloat16*)(ws + 32 * MB);
  __hip_bfloat16* Kb  = (__hip_bfloat16*)(ws + 64 * MB);
  __hip_bfloat16* Vtb = (__hip_bfloat16*)(ws + 96 * MB);
  __hip_bfloat16* AOb = (__hip_bfloat16*)(ws + 128 * MB);
  __hip_bfloat16* FF1 = (__hip_bfloat16*)(ws + 32 * MB);   // after O-proj, 128M
  __hip_bfloat16* WqT = (__hip_bfloat16*)(ws + 160 * MB);
  __hip_bfloat16* WkT = (__hip_bfloat16*)(ws + 168 * MB);
  __hip_bfloat16* WvT = (__hip_bfloat16*)(ws + 176 * MB);
  __hip_bfloat16* WoT = (__hip_bfloat16*)(ws + 184 * MB);
  __hip_bfloat16* W1T = (__hip_bfloat16*)(ws + 160 * MB);  // after O-proj
  __hip_bfloat16* W2T = (__hip_bfloat16*)(ws + 160 * MB);  // after FF1
  float* X2 = (float*)d_out;  // residual stream lives in d_out

  const dim3 tb(256);
  transpose_cvt_kernel<<<dim3(64, 64), tb, 0, stream>>>(Wq, WqT, 2048, 2048);
  transpose_cvt_kernel<<<dim3(64, 64), tb, 0, stream>>>(Wk, WkT, 2048, 2048);
  transpose_cvt_kernel<<<dim3(64, 64), tb, 0, stream>>>(Wv, WvT, 2048, 2048);
  transpose_cvt_kernel<<<dim3(64, 64), tb, 0, stream>>>(Wo, WoT, 2048, 2048);

  layernorm_kernel<<<MTOT, tb, 0, stream>>>(x, g1, be1, Hb);

  // QKV/O-proj: M=8192, N=2048 -> 256 blocks (XCD window 4r x 8c)
  gemm_kernel<EPI_BF16><<<256, 512, 0, stream>>>(Hb, WqT, bq, nullptr, Qb, MTOT, 2048, 2048);
  gemm_kernel<EPI_BF16><<<256, 512, 0, stream>>>(Hb, WkT, bk, nullptr, Kb, MTOT, 2048, 2048);
  gemm_kernel<EPI_VT><<<256, 512, 0, stream>>>(Hb, WvT, bv, nullptr, Vtb, MTOT, 2048, 2048);

  attn_kernel<<<dim3(SEQ / 128, BATCH * NUM_HEADS), dim3(512), 0, stream>>>(Qb, Kb, Vtb, AOb);

  gemm_kernel<EPI_RESID><<<256, 512, 0, stream>>>(AOb, WoT, bo, x, X2, MTOT, 2048, 2048);

  layernorm_kernel<<<MTOT, tb, 0, stream>>>(X2, g2, be2, Hb);

  // FFN full-M: W1T into dead small-weight region, FF1 into dead Q/K/Vt/AO
  transpose_cvt_kernel<<<dim3(256, 64), tb, 0, stream>>>(W1, W1T, 2048, 8192);
  // FF1: M=8192, N=8192 -> 1024 blocks
  gemm_kernel<EPI_GELU><<<1024, 512, 0, stream>>>(Hb, W1T, b1, nullptr, FF1, MTOT, 8192, 2048);
  // W2T overwrites W1T (dead after FF1)
  transpose_cvt_kernel<<<dim3(64, 256), tb, 0, stream>>>(W2, W2T, 8192, 2048);
  // FF2: M=8192, N=2048, K=8192 -> 256 blocks
  gemm_kernel<EPI_RESID><<<256, 512, 0, stream>>>(FF1, W2T, b2, X2, X2, MTOT, 2048, 8192);
}

// Round 14
// 1176.355 us; speedup vs baseline: 1.0710x; 1.0116x over previous
//
#include <hip/hip_runtime.h>
#include <hip/hip_bf16.h>

#define D_MODEL 2048
#define NUM_HEADS 16
#define D_FF 8192
#define BATCH 4
#define SEQ 2048
#define DK 128
#define MTOT (BATCH * SEQ)  // 8192

typedef __attribute__((ext_vector_type(8))) short short8;
typedef __attribute__((ext_vector_type(4))) short short4v;
typedef __attribute__((ext_vector_type(4))) float f32x4;

#define MFMA16(a, b, c) __builtin_amdgcn_mfma_f32_16x16x32_bf16(a, b, c, 0, 0, 0)

#define GLOAD16(gp, lp)                                                        \
  __builtin_amdgcn_global_load_lds(                                            \
      (const __attribute__((address_space(1))) void*)(gp),                     \
      (__attribute__((address_space(3))) void*)(lp), 16, 0, 0)

// raw barrier: compiler cannot attach an implicit vmcnt/lgkm drain to an asm
// block (hypothesis test vs __builtin_amdgcn_s_barrier)
#define SBAR() asm volatile("s_barrier" ::: "memory")

static __device__ __forceinline__ unsigned short f2bf(float f) {
  return __builtin_bit_cast(unsigned short, __float2bfloat16(f));
}

// ---------------------------------------------------------------------------
// Weight convert + transpose: in f32 [K][N] -> out bf16 [N][K]
// ---------------------------------------------------------------------------
__global__ __launch_bounds__(256) void transpose_cvt_kernel(
    const float* __restrict__ in, __hip_bfloat16* __restrict__ out, int K, int N) {
  __shared__ float tile[32][33];
  const int n0 = blockIdx.x * 32, k0 = blockIdx.y * 32;
  const int tx = threadIdx.x & 31, ty = threadIdx.x >> 5;  // 32 x 8
#pragma unroll
  for (int i = 0; i < 4; ++i)
    tile[ty + i * 8][tx] = in[(size_t)(k0 + ty + i * 8) * N + n0 + tx];
  __syncthreads();
#pragma unroll
  for (int i = 0; i < 4; ++i)
    out[(size_t)(n0 + ty + i * 8) * K + k0 + tx] = __float2bfloat16(tile[tx][ty + i * 8]);
}

// 4 small [2048][2048] weights in one launch (z selects the matrix)
__global__ __launch_bounds__(256) void transpose_cvt4_kernel(
    const float* __restrict__ s0, const float* __restrict__ s1,
    const float* __restrict__ s2, const float* __restrict__ s3,
    __hip_bfloat16* __restrict__ d0, __hip_bfloat16* __restrict__ d1,
    __hip_bfloat16* __restrict__ d2, __hip_bfloat16* __restrict__ d3) {
  const int z = blockIdx.z;
  const float* in = z == 0 ? s0 : (z == 1 ? s1 : (z == 2 ? s2 : s3));
  __hip_bfloat16* out = z == 0 ? d0 : (z == 1 ? d1 : (z == 2 ? d2 : d3));
  __shared__ float tile[32][33];
  const int n0 = blockIdx.x * 32, k0 = blockIdx.y * 32;
  const int tx = threadIdx.x & 31, ty = threadIdx.x >> 5;
#pragma unroll
  for (int i = 0; i < 4; ++i)
    tile[ty + i * 8][tx] = in[(size_t)(k0 + ty + i * 8) * 2048 + n0 + tx];
  __syncthreads();
#pragma unroll
  for (int i = 0; i < 4; ++i)
    out[(size_t)(n0 + ty + i * 8) * 2048 + k0 + tx] =
        __float2bfloat16(tile[tx][ty + i * 8]);
}

// ---------------------------------------------------------------------------
// LayerNorm: f32 [M][D_MODEL] -> bf16 [M][D_MODEL]
// ---------------------------------------------------------------------------
__global__ __launch_bounds__(256) void layernorm_kernel(
    const float* __restrict__ x, const float* __restrict__ g,
    const float* __restrict__ bta, __hip_bfloat16* __restrict__ out) {
  const int row = blockIdx.x;
  const int tid = threadIdx.x;
  const float* xr = x + (size_t)row * D_MODEL;
  float4 v0 = *(const float4*)(xr + tid * 8);
  float4 v1 = *(const float4*)(xr + tid * 8 + 4);
  float s = v0.x + v0.y + v0.z + v0.w + v1.x + v1.y + v1.z + v1.w;
  float q = v0.x * v0.x + v0.y * v0.y + v0.z * v0.z + v0.w * v0.w +
            v1.x * v1.x + v1.y * v1.y + v1.z * v1.z + v1.w * v1.w;
#pragma unroll
  for (int off = 1; off < 64; off <<= 1) {
    s += __shfl_xor(s, off);
    q += __shfl_xor(q, off);
  }
  __shared__ float rs[4], rq[4];
  if ((tid & 63) == 0) {
    rs[tid >> 6] = s;
    rq[tid >> 6] = q;
  }
  __syncthreads();
  s = rs[0] + rs[1] + rs[2] + rs[3];
  q = rq[0] + rq[1] + rq[2] + rq[3];
  const float mu = s * (1.0f / D_MODEL);
  const float var = q * (1.0f / D_MODEL) - mu * mu;
  const float rstd = rsqrtf(var + 1e-5f);
  float4 g0 = *(const float4*)(g + tid * 8);
  float4 g1 = *(const float4*)(g + tid * 8 + 4);
  float4 b0 = *(const float4*)(bta + tid * 8);
  float4 b1 = *(const float4*)(bta + tid * 8 + 4);
  short8 o;
  o[0] = (short)f2bf((v0.x - mu) * rstd * g0.x + b0.x);
  o[1] = (short)f2bf((v0.y - mu) * rstd * g0.y + b0.y);
  o[2] = (short)f2bf((v0.z - mu) * rstd * g0.z + b0.z);
  o[3] = (short)f2bf((v0.w - mu) * rstd * g0.w + b0.w);
  o[4] = (short)f2bf((v1.x - mu) * rstd * g1.x + b1.x);
  o[5] = (short)f2bf((v1.y - mu) * rstd * g1.y + b1.y);
  o[6] = (short)f2bf((v1.z - mu) * rstd * g1.z + b1.z);
  o[7] = (short)f2bf((v1.w - mu) * rstd * g1.w + b1.w);
  *(short8*)(out + (size_t)row * D_MODEL + tid * 8) = o;
}

// ---------------------------------------------------------------------------
// GEMM v7: 256x256 tile, BK=64, 8 waves (2Mx4N), dbuf LDS (128K).
// 4 phases/K-tile, raw-asm s_barrier (no compiler waitcnt attachment),
// counted vmcnt(7) once per K-tile. XCD decode: 4r x 8c window per XCD.
// EPI_QKV: fused Q/K/V epilogue keyed on n>>11 (N=6144, Bt=WqkvT contig).
// ---------------------------------------------------------------------------
enum { EPI_BF16 = 0, EPI_VT = 1, EPI_RESID = 2, EPI_GELU = 3, EPI_QKV = 4 };

#define AF_MFMA_PHASE(FI0)                                                     \
  {                                                                            \
    const int raA = wm + (FI0) * 16 + l15;                                     \
    const int raB = wm + ((FI0) + 1) * 16 + l15;                               \
    short8 aA0 = *(const short8*)(db + raA * 128 + ((lg ^ (raA & 7)) << 4));   \
    short8 aB0 = *(const short8*)(db + raB * 128 + ((lg ^ (raB & 7)) << 4));   \
    short8 aA1 =                                                               \
        *(const short8*)(db + raA * 128 + (((4 + lg) ^ (raA & 7)) << 4));      \
    short8 aB1 =                                                               \
        *(const short8*)(db + raB * 128 + (((4 + lg) ^ (raB & 7)) << 4));      \
    SBAR();                                                                    \
    asm volatile("s_waitcnt lgkmcnt(0)" ::: "memory");                         \
    __builtin_amdgcn_sched_barrier(0);                                         \
    __builtin_amdgcn_s_setprio(1);                                             \
    _Pragma("unroll") for (int fj = 0; fj < 4; ++fj)                           \
        acc[FI0][fj] = MFMA16(aA0, bf0[fj], acc[FI0][fj]);                     \
    _Pragma("unroll") for (int fj = 0; fj < 4; ++fj)                           \
        acc[(FI0) + 1][fj] = MFMA16(aB0, bf0[fj], acc[(FI0) + 1][fj]);         \
    _Pragma("unroll") for (int fj = 0; fj < 4; ++fj)                           \
        acc[FI0][fj] = MFMA16(aA1, bf1[fj], acc[FI0][fj]);                     \
    _Pragma("unroll") for (int fj = 0; fj < 4; ++fj)                           \
        acc[(FI0) + 1][fj] = MFMA16(aB1, bf1[fj], acc[(FI0) + 1][fj]);         \
    __builtin_amdgcn_s_setprio(0);                                             \
  }

template <int EPI>
__global__ __launch_bounds__(512, 2) void gemm_kernel(
    const __hip_bfloat16* __restrict__ A, const __hip_bfloat16* __restrict__ Bt,
    const float* __restrict__ bias, const float* __restrict__ bias2,
    const float* __restrict__ bias3, const float* __restrict__ resid,
    void* __restrict__ outv, void* __restrict__ out2, void* __restrict__ out3,
    int M, int N, int K) {
  __shared__ __align__(16) unsigned char lds[2][65536];  // [dbuf][A 32K | B 32K]
  const int tid = threadIdx.x;
  const int lane = tid & 63, w = tid >> 6;  // 8 waves
  const int l15 = lane & 15, lg = lane >> 4;
  const int d = blockIdx.x;
  const int x = d & 7;   // XCD (round-robin dispatch)
  const int i = d >> 3;  // within-XCD index
  const int cC = (i & 7) + 8 * (i >> 5);
  const int rC = x + 8 * ((i >> 3) & 3);
  const int m0 = rC * 256, n0 = cC * 256;
  const int wm = (w >> 2) * 128, wn = (w & 3) * 64;

  f32x4 acc[8][4] = {};

  const int row8 = lane >> 3;        // 0..7 (row within 8-row chunk)
  const int g8 = (lane & 7) ^ row8;  // pre-swizzled source 16B-block
  const int wa = (w & 3) + ((w >> 2) * 16);  // A-chunk base for this wave

  auto stA = [&](int tt, int c) {
    GLOAD16(A + (size_t)(m0 + c * 8 + row8) * K + (size_t)tt * 64 + g8 * 8,
            lds[tt & 1] + c * 1024);
  };
  auto stB = [&](int tt, int c) {
    GLOAD16(Bt + (size_t)(n0 + c * 8 + row8) * K + (size_t)tt * 64 + g8 * 8,
            lds[tt & 1] + 32768 + c * 1024);
  };

  const int nt = K >> 6;  // K-tiles of 64

  // prologue: tile0 all 8 loads, tile1 first 7 (A-q3 of tile1 staged at t0.P0)
  stB(0, w); stB(0, 8 + w); stA(0, wa);
  stB(0, 16 + w); stB(0, 24 + w); stA(0, wa + 4);
  stA(0, wa + 8); stA(0, wa + 12);
  stB(1, w); stB(1, 8 + w); stA(1, wa);
  stB(1, 16 + w); stB(1, 24 + w); stA(1, wa + 4);
  stA(1, wa + 8);
  asm volatile("s_waitcnt vmcnt(7)" ::: "memory");  // tile0 fully in LDS
  SBAR();

  for (int t = 0; t < nt; ++t) {
    const unsigned char* db = lds[t & 1];
    const bool s1 = (t + 1 < nt), s2 = (t + 2 < nt);
    short8 bf0[4], bf1[4];
    // ---------------- P0: bf(all) + af fi0,1 ----------------
    if (s1) stA(t + 1, wa + 12);  // A-q3 of t+1 (dead since (t-1).P3)
#pragma unroll
    for (int f = 0; f < 4; ++f) {
      const int rb = wn + f * 16 + l15;
      bf0[f] = *(const short8*)(db + 32768 + rb * 128 + ((lg ^ (rb & 7)) << 4));
      bf1[f] =
          *(const short8*)(db + 32768 + rb * 128 + (((4 + lg) ^ (rb & 7)) << 4));
    }
    AF_MFMA_PHASE(0)
    SBAR();  // end P0: B + A-q0 of tile t dead
    // ---------------- P1: af fi2,3 ----------------
    if (s2) { stB(t + 2, w); stB(t + 2, 8 + w); stA(t + 2, wa); }
    AF_MFMA_PHASE(2)
    SBAR();  // end P1: A-q1 dead
    // ---------------- P2: af fi4,5 ----------------
    if (s2) { stB(t + 2, 16 + w); stB(t + 2, 24 + w); stA(t + 2, wa + 4); }
    AF_MFMA_PHASE(4)
    SBAR();  // end P2: A-q2 dead
    // ---------------- P3: af fi6,7 ----------------
    if (s2) stA(t + 2, wa + 8);
    AF_MFMA_PHASE(6)
    if (s2)
      asm volatile("s_waitcnt vmcnt(7)" ::: "memory");  // t+1's 8 retired
    else
      asm volatile("s_waitcnt vmcnt(0)" ::: "memory");
    SBAR();  // end P3: next tile's reads now safe
  }

#pragma unroll
  for (int fi = 0; fi < 8; ++fi) {
#pragma unroll
    for (int fj = 0; fj < 4; ++fj) {
      const int mb = m0 + wm + fi * 16 + lg * 4;
      const int n = n0 + wn + fj * 16 + l15;
      if constexpr (EPI == EPI_QKV) {
        const int sec = n >> 11;  // 0=Q, 1=K, 2=V
        const int nn = n & 2047;
        const float bv = sec == 0 ? bias[nn] : (sec == 1 ? bias2[nn] : bias3[nn]);
        if (sec < 2) {
          __hip_bfloat16* o = sec == 0 ? (__hip_bfloat16*)outv : (__hip_bfloat16*)out2;
#pragma unroll
          for (int r = 0; r < 4; ++r)
            o[(size_t)(mb + r) * 2048 + nn] = __float2bfloat16(acc[fi][fj][r] + bv);
        } else {
          // V^T: out bf16 [B][H][DK][SEQ]
          const int bb = mb >> 11, ss = mb & (SEQ - 1);
          const int hh = nn >> 7, dd = nn & (DK - 1);
          short4v pk;
#pragma unroll
          for (int r = 0; r < 4; ++r) pk[r] = (short)f2bf(acc[fi][fj][r] + bv);
          __hip_bfloat16* o = (__hip_bfloat16*)out3;
          *(short4v*)(o + ((size_t)((bb * NUM_HEADS + hh) * DK + dd)) * SEQ + ss) = pk;
        }
      } else {
        const float bv = bias ? bias[n] : 0.0f;
        if constexpr (EPI == EPI_VT) {
          const int bb = mb >> 11, ss = mb & (SEQ - 1);
          const int hh = n >> 7, dd = n & (DK - 1);
          short4v pk;
#pragma unroll
          for (int r = 0; r < 4; ++r) pk[r] = (short)f2bf(acc[fi][fj][r] + bv);
          __hip_bfloat16* o = (__hip_bfloat16*)outv;
          *(short4v*)(o + ((size_t)((bb * NUM_HEADS + hh) * DK + dd)) * SEQ + ss) = pk;
        } else {
#pragma unroll
          for (int r = 0; r < 4; ++r) {
            const int m = mb + r;
            const float v = acc[fi][fj][r] + bv;
            if constexpr (EPI == EPI_BF16) {
              ((__hip_bfloat16*)outv)[(size_t)m * N + n] = __float2bfloat16(v);
            } else if constexpr (EPI == EPI_GELU) {
              const float ge = 0.5f * v * (1.0f + erff(v * 0.70710678118654752f));
              ((__hip_bfloat16*)outv)[(size_t)m * N + n] = __float2bfloat16(ge);
            } else {  // EPI_RESID (resid may alias outv: same-element r->w)
              ((float*)outv)[(size_t)m * N + n] = resid[(size_t)m * N + n] + v;
            }
          }
        }
      }
    }
  }
}

// ---------------------------------------------------------------------------
// Flash attention (causal), swapped-QK^T in-register softmax (round-13).
// Raw-asm barriers (same hypothesis test). LDS 64KB, 2 blocks/CU.
// ---------------------------------------------------------------------------
__global__ __launch_bounds__(512, 4) void attn_kernel(
    const __hip_bfloat16* __restrict__ Qm, const __hip_bfloat16* __restrict__ Km,
    const __hip_bfloat16* __restrict__ Vt, __hip_bfloat16* __restrict__ Om) {
  __shared__ __align__(16) unsigned char Kl[2][16384];  // [64 t][128 d] swizzled
  __shared__ __align__(16) unsigned char Vl[2][16384];  // [128 d][64 t] swizzled
  const int tid = threadIdx.x;
  const int lane = tid & 63, w = tid >> 6;  // w in 0..7
  const int l15 = lane & 15, lg = lane >> 4;
  const int bh = blockIdx.y, b = bh >> 4, h = bh & 15;
  const int q0 = ((int)gridDim.x - 1 - (int)blockIdx.x) * 128;  // LPT order
  const int qw = q0 + w * 16;
  const int row8 = lane >> 3;
  const int nt = (q0 >> 6) + 2;  // K/V tiles 0 .. q0/64+1

  // Q fragments: row/col = l15 (A and B layouts coincide), k = ks*32 + lg*8
  short8 qf[4];
  const __hip_bfloat16* qbase = Qm + (size_t)(b * SEQ + qw + l15) * D_MODEL + h * DK;
#pragma unroll
  for (int ks = 0; ks < 4; ++ks) qf[ks] = *(const short8*)(qbase + ks * 32 + lg * 8);

  float m_run = -1e30f, l_run = 0.0f;  // stats for q = qw + l15 (x4 replicas)
  f32x4 acc_o[8];
#pragma unroll
  for (int fd = 0; fd < 8; ++fd) acc_o[fd] = (f32x4){0.f, 0.f, 0.f, 0.f};

  auto STAGE = [&](int tt) {
    unsigned char* kb = Kl[tt & 1];
    unsigned char* vb = Vl[tt & 1];
    const int t0s = tt * 64;
#pragma unroll
    for (int i = 0; i < 2; ++i) {
      const int c = w * 2 + i;
      const int row = c * 4 + lg;
      const int gcb = l15 ^ (row & 7);
      GLOAD16(Km + (size_t)(b * SEQ + t0s + row) * D_MODEL + h * DK + gcb * 8,
              kb + c * 1024);
    }
#pragma unroll
    for (int i = 0; i < 2; ++i) {
      const int c = w * 2 + i;
      const int row = c * 8 + row8;
      const int gcb = (lane & 7) ^ (row & 7);
      GLOAD16(Vt + (size_t)(bh * DK + row) * SEQ + t0s + gcb * 8, vb + c * 1024);
    }
  };

  STAGE(0);
  for (int t = 0; t < nt; ++t) {
    const int t0 = t * 64;
    if (t + 1 < nt) {
      STAGE(t + 1);  // 4 loads -> in flight across this tile's compute
      asm volatile("s_waitcnt vmcnt(4)" ::: "memory");  // tile t complete
    } else {
      asm volatile("s_waitcnt vmcnt(0)" ::: "memory");
    }
    SBAR();  // all waves: tile t in LDS; t-1 reads done
    if (t0 <= qw + 15) {
      const unsigned char* kb = Kl[t & 1];
      const unsigned char* vb = Vl[t & 1];
      // S^T = K Q : lane (l15, lg) gets P[q=qw+l15][key = t0+fn*16+lg*4+r]
      f32x4 sacc[4];
#pragma unroll
      for (int fn = 0; fn < 4; ++fn) sacc[fn] = (f32x4){0.f, 0.f, 0.f, 0.f};
      __builtin_amdgcn_s_setprio(1);
#pragma unroll
      for (int ks = 0; ks < 4; ++ks) {
        const int cb = ks * 4 + lg;
#pragma unroll
        for (int fn = 0; fn < 4; ++fn) {
          const int rn = fn * 16 + l15;
          short8 kf = *(const short8*)(kb + rn * 256 + ((cb ^ (rn & 7)) << 4));
          sacc[fn] = MFMA16(kf, qf[ks], sacc[fn]);  // swapped operands
        }
      }
      __builtin_amdgcn_s_setprio(0);
      const float scale = 0.088388347648318447f;  // 1/sqrt(128)
      const int qg = qw + l15;
      float mt = -1e30f;
#pragma unroll
      for (int fn = 0; fn < 4; ++fn) {
        const int keyb = t0 + fn * 16 + lg * 4;
#pragma unroll
        for (int r = 0; r < 4; ++r) {
          float sv = sacc[fn][r] * scale;
          sv = (keyb + r <= qg) ? sv : -1e30f;
          sacc[fn][r] = sv;
          mt = fmaxf(mt, sv);
        }
      }
      mt = fmaxf(mt, __shfl_xor(mt, 16));
      mt = fmaxf(mt, __shfl_xor(mt, 32));
      // defer-max (T13)
      const bool defer = __all(mt <= m_run + 8.0f);
      float alpha = 1.0f;
      if (!defer) {
        const float mnew = fmaxf(m_run, mt);
        alpha = __expf(m_run - mnew);
        m_run = mnew;
      }
      float ls = 0.0f;
#pragma unroll
      for (int fn = 0; fn < 4; ++fn)
#pragma unroll
        for (int r = 0; r < 4; ++r) {
          const float p = __expf(sacc[fn][r] - m_run);
          sacc[fn][r] = p;
          ls += p;
        }
      ls += __shfl_xor(ls, 16);
      ls += __shfl_xor(ls, 32);
      l_run = (defer ? l_run : l_run * alpha) + ls;
      if (!defer) {
        float abr[4];
#pragma unroll
        for (int r = 0; r < 4; ++r) abr[r] = __shfl(alpha, lg * 4 + r);
#pragma unroll
        for (int fd = 0; fd < 8; ++fd)
#pragma unroll
          for (int r = 0; r < 4; ++r) acc_o[fd][r] *= abr[r];
      }
      // P pack: pf[j] = P[q=l15][t = s*32 + lg*8 + j] via shfl+select
      const int srcLo = l15 + 16 * (2 * (lg & 1));
      const int srcHi = srcLo + 16;
      const int hi = lg >> 1;
#pragma unroll
      for (int s = 0; s < 2; ++s) {
        short8 pf;
#pragma unroll
        for (int j = 0; j < 4; ++j) {
          const float v0 = __shfl(sacc[2 * s][j], srcLo);
          const float v1 = __shfl(sacc[2 * s + 1][j], srcLo);
          pf[j] = (short)f2bf(hi ? v1 : v0);
          const float w0 = __shfl(sacc[2 * s][j], srcHi);
          const float w1 = __shfl(sacc[2 * s + 1][j], srcHi);
          pf[4 + j] = (short)f2bf(hi ? w1 : w0);
        }
        const int cb = s * 4 + lg;
        __builtin_amdgcn_s_setprio(1);
#pragma unroll
        for (int fd = 0; fd < 8; ++fd) {
          const int rv = fd * 16 + l15;
          short8 vf = *(const short8*)(vb + rv * 128 + ((cb ^ (rv & 7)) << 4));
          acc_o[fd] = MFMA16(pf, vf, acc_o[fd]);
        }
        __builtin_amdgcn_s_setprio(0);
      }
    }
    asm volatile("s_waitcnt lgkmcnt(0)" ::: "memory");  // my LDS reads done
    SBAR();  // all reads of buf[t&1] done before t+2 stages it
  }
  // epilogue: q = qw + lg*4 + r, d = fd*16 + l15
  float linv[4];
#pragma unroll
  for (int r = 0; r < 4; ++r) linv[r] = __shfl(l_run, lg * 4 + r);
#pragma unroll
  for (int r = 0; r < 4; ++r) {
    const float inv = 1.0f / linv[r];
    const int qg = qw + lg * 4 + r;
    __hip_bfloat16* ob = Om + (size_t)(b * SEQ + qg) * D_MODEL + h * DK + l15;
#pragma unroll
    for (int fd = 0; fd < 8; ++fd)
      ob[fd * 16] = __float2bfloat16(acc_o[fd][r] * inv);
  }
}

// ---------------------------------------------------------------------------
// Workspace layout (192 MiB peak, time-shared):
//   @0   Hb (32M)  LN1 out -> later LN2 out
//   @32  Qb (32M) -\
//   @64  Kb (32M)  |-> after O-proj: FF1 full tensor (128M, 8192x8192 bf16)
//   @96  Vt (32M)  |
//   @128 AO (32M) -/
//   @160 WqT/WkT/WvT (24M contig = WqkvT[6144][2048]) + WoT@184 (8M)
//        -> after O-proj: W1T (32M) -> after FF1: W2T (32M)
// X2 (f32 residual stream) lives in d_out itself.
// ---------------------------------------------------------------------------
extern "C" void kernel_launch(void* const* d_in, const int* in_sizes, int n_in,
                              void* d_out, int out_size, void* d_ws, size_t ws_size,
                              hipStream_t stream) {
  (void)in_sizes; (void)n_in; (void)out_size;
  const size_t MB = 1024 * 1024;
  if (ws_size < 192 * MB) return;  // diagnostic guard

  const float* x  = (const float*)d_in[0];
  const float* Wq = (const float*)d_in[1];
  const float* bq = (const float*)d_in[2];
  const float* Wk = (const float*)d_in[3];
  const float* bk = (const float*)d_in[4];
  const float* Wv = (const float*)d_in[5];
  const float* bv = (const float*)d_in[6];
  const float* Wo = (const float*)d_in[7];
  const float* bo = (const float*)d_in[8];
  const float* W1 = (const float*)d_in[9];
  const float* b1 = (const float*)d_in[10];
  const float* W2 = (const float*)d_in[11];
  const float* b2 = (const float*)d_in[12];
  const float* g1 = (const float*)d_in[13];
  const float* be1 = (const float*)d_in[14];
  const float* g2 = (const float*)d_in[15];
  const float* be2 = (const float*)d_in[16];

  char* ws = (char*)d_ws;
  __hip_bfloat16* Hb  = (__hip_bfloat16*)(ws + 0 * MB);
  __hip_bfloat16* Qb  = (__hip_bfloat16*)(ws + 32 * MB);
  __hip_bfloat16* Kb  = (__hip_bfloat16*)(ws + 64 * MB);
  __hip_bfloat16* Vtb = (__hip_bfloat16*)(ws + 96 * MB);
  __hip_bfloat16* AOb = (__hip_bfloat16*)(ws + 128 * MB);
  __hip_bfloat16* FF1 = (__hip_bfloat16*)(ws + 32 * MB);   // after O-proj, 128M
  __hip_bfloat16* WqkvT = (__hip_bfloat16*)(ws + 160 * MB);  // [6144][2048]
  __hip_bfloat16* WqT = (__hip_bfloat16*)(ws + 160 * MB);
  __hip_bfloat16* WkT = (__hip_bfloat16*)(ws + 168 * MB);
  __hip_bfloat16* WvT = (__hip_bfloat16*)(ws + 176 * MB);
  __hip_bfloat16* WoT = (__hip_bfloat16*)(ws + 184 * MB);
  __hip_bfloat16* W1T = (__hip_bfloat16*)(ws + 160 * MB);  // after O-proj
  __hip_bfloat16* W2T = (__hip_bfloat16*)(ws + 160 * MB);  // after FF1
  float* X2 = (float*)d_out;  // residual stream lives in d_out

  const dim3 tb(256);
  transpose_cvt4_kernel<<<dim3(64, 64, 4), tb, 0, stream>>>(
      Wq, Wk, Wv, Wo, WqT, WkT, WvT, WoT);

  layernorm_kernel<<<MTOT, tb, 0, stream>>>(x, g1, be1, Hb);

  // Fused QKV: M=8192, N=6144 -> 768 blocks (XCD window 4r x 8c, bijective)
  gemm_kernel<EPI_QKV><<<768, 512, 0, stream>>>(
      Hb, WqkvT, bq, bk, bv, nullptr, Qb, Kb, Vtb, MTOT, 6144, 2048);

  attn_kernel<<<dim3(SEQ / 128, BATCH * NUM_HEADS), dim3(512), 0, stream>>>(Qb, Kb, Vtb, AOb);

  gemm_kernel<EPI_RESID><<<256, 512, 0, stream>>>(
      AOb, WoT, bo, nullptr, nullptr, x, X2, nullptr, nullptr, MTOT, 2048, 2048);

  layernorm_kernel<<<MTOT, tb, 0, stream>>>(X2, g2, be2, Hb);

  // FFN full-M: W1T into dead small-weight region, FF1 into dead Q/K/Vt/AO
  transpose_cvt_kernel<<<dim3(256, 64), tb, 0, stream>>>(W1, W1T, 2048, 8192);
  gemm_kernel<EPI_GELU><<<1024, 512, 0, stream>>>(
      Hb, W1T, b1, nullptr, nullptr, nullptr, FF1, nullptr, nullptr, MTOT, 8192, 2048);
  transpose_cvt_kernel<<<dim3(64, 256), tb, 0, stream>>>(W2, W2T, 8192, 2048);
  gemm_kernel<EPI_RESID><<<256, 512, 0, stream>>>(
      FF1, W2T, b2, nullptr, nullptr, X2, X2, nullptr, nullptr, MTOT, 2048, 8192);
}